// Round 5
// baseline (2972.892 us; speedup 1.0000x reference)
//
#include <hip/hip_runtime.h>

#define N_ALL 4096
#define N_LAB 1024
#define DIMF 1024
#define EDGECAP 32768
#define GCAP 12288
#define ALPHA_ 0.99f
#define NIT_CH 80
#define EPS_D 2.220446049250313e-16

typedef short bf16x8 __attribute__((ext_vector_type(8)));
typedef float f32x4 __attribute__((ext_vector_type(4)));

struct __align__(8) Edge { unsigned j; float w; };

__device__ inline const float* xrow(const float* L, const float* U, int r) {
  return (r < N_LAB) ? (L + (size_t)r * DIMF) : (U + (size_t)(r - N_LAB) * DIMF);
}

__device__ inline void load_lds16(const void* g, void* l) {
  __builtin_amdgcn_global_load_lds(
      (const __attribute__((address_space(1))) unsigned int*)g,
      (__attribute__((address_space(3))) unsigned int*)l, 16, 0, 0);
}

__device__ inline unsigned short bf16rne(float f) {
  unsigned u = __float_as_uint(f);
  unsigned r = (u + 0x7fffu + ((u >> 16) & 1u)) >> 16;
  return (unsigned short)r;
}

// ------- prep: fp32 -> bf16 copy + fp32 & fp64 row norms — verbatim -------
__global__ __launch_bounds__(256) void prep_k(const float* __restrict__ L,
                                              const float* __restrict__ U,
                                              unsigned short* __restrict__ Xbf,
                                              float* __restrict__ sq,
                                              double* __restrict__ sqd) {
  const int row = blockIdx.x;
  const int tid = threadIdx.x;
  const float* src = xrow(L, U, row);
  float4 v = ((const float4*)src)[tid];
  ushort4 h;
  h.x = bf16rne(v.x); h.y = bf16rne(v.y); h.z = bf16rne(v.z); h.w = bf16rne(v.w);
  ((ushort4*)(Xbf + (size_t)row * DIMF))[tid] = h;
  float s = v.x * v.x + v.y * v.y + v.z * v.z + v.w * v.w;
  double sd = (double)v.x * v.x + (double)v.y * v.y +
              (double)v.z * v.z + (double)v.w * v.w;
#pragma unroll
  for (int d = 32; d >= 1; d >>= 1) {
    s += __shfl_xor(s, d);
    sd += __shfl_xor(sd, d);
  }
  __shared__ float wsum[4];
  __shared__ double wsumd[4];
  if ((tid & 63) == 0) { wsum[tid >> 6] = s; wsumd[tid >> 6] = sd; }
  __syncthreads();
  if (tid == 0) {
    sq[row] = wsum[0] + wsum[1] + wsum[2] + wsum[3];
    sqd[row] = wsumd[0] + wsumd[1] + wsumd[2] + wsumd[3];
  }
}

// ------- MFMA bf16 gram -> fp16 RANKING PROXY — verbatim -------
__global__ __launch_bounds__(256) void gemm_w(const unsigned short* __restrict__ Xbf,
                                              const float* __restrict__ sq,
                                              _Float16* __restrict__ Wh) {
  __shared__ unsigned short At[128 * 32];
  __shared__ unsigned short Bt[128 * 32];
  const int tid = threadIdx.x;
  const int wave = tid >> 6, lane = tid & 63;
  const int brow = blockIdx.y * 128, bcol = blockIdx.x * 128;
  const int q = lane >> 4, rl = lane & 15;
  const int wr = (wave >> 1) * 64, wc = (wave & 1) * 64;

  f32x4 acc[4][4] = {};

  const int srow = tid >> 2;
  const int soff = (tid & 3) * 8;

  for (int k0 = 0; k0 < DIMF; k0 += 32) {
#pragma unroll
    for (int half = 0; half < 2; ++half) {
      const unsigned short* ga =
          Xbf + (size_t)(brow + half * 64 + srow) * DIMF + k0 + soff;
      load_lds16(ga, &At[(half * 64 + wave * 16) * 32]);
      const unsigned short* gb =
          Xbf + (size_t)(bcol + half * 64 + srow) * DIMF + k0 + soff;
      load_lds16(gb, &Bt[(half * 64 + wave * 16) * 32]);
    }
    __syncthreads();
    bf16x8 af[4], bf_[4];
#pragma unroll
    for (int t = 0; t < 4; ++t) {
      af[t] = *(const bf16x8*)&At[(wr + t * 16 + rl) * 32 + q * 8];
      bf_[t] = *(const bf16x8*)&Bt[(wc + t * 16 + rl) * 32 + q * 8];
    }
#pragma unroll
    for (int i = 0; i < 4; ++i)
#pragma unroll
      for (int j = 0; j < 4; ++j)
        acc[i][j] = __builtin_amdgcn_mfma_f32_16x16x32_bf16(af[i], bf_[j], acc[i][j], 0, 0, 0);
    __syncthreads();
  }

#pragma unroll
  for (int i = 0; i < 4; ++i) {
#pragma unroll
    for (int j = 0; j < 4; ++j) {
#pragma unroll
      for (int reg = 0; reg < 4; ++reg) {
        int gr = brow + wr + i * 16 + q * 4 + reg;
        int gc = bcol + wc + j * 16 + rl;
        float g = acc[i][j][reg];
        float dist = sq[gr] + sq[gc] - 2.0f * g;   // unnormalized
        float val = fmaxf(2600.0f - dist, 0.25f);
        if (gr == gc) val = 0.0f;
        Wh[(size_t)gr * N_ALL + gc] = (_Float16)val;
      }
    }
  }
}

// ------- top-8 candidates per row (fp16 proxy), single scan — verbatim -------
__global__ __launch_bounds__(256) void top8_k(const _Float16* __restrict__ Wh,
                                              unsigned* __restrict__ t8i) {
  const int wave = threadIdx.x >> 6, lane = threadIdx.x & 63;
  const int row = blockIdx.x * 4 + wave;
  const _Float16* Wr = Wh + (size_t)row * N_ALL;
  float bv[8]; unsigned bj[8];
#pragma unroll
  for (int t = 0; t < 8; ++t) { bv[t] = -1.0f; bj[t] = 0xFFFFFFFFu; }
  float minv = -1.0f; int mins = 0;
  for (int s = 0; s < 64; ++s) {
    int j = s * 64 + lane;
    float v = (float)Wr[j];
    if (v > minv) {
#pragma unroll
      for (int t = 0; t < 8; ++t) if (t == mins) { bv[t] = v; bj[t] = (unsigned)j; }
      minv = bv[0]; mins = 0;
#pragma unroll
      for (int t = 1; t < 8; ++t) if (bv[t] < minv) { minv = bv[t]; mins = t; }
    }
  }
  for (int pick = 0; pick < 8; ++pick) {
    unsigned long long best = 0;
#pragma unroll
    for (int t = 0; t < 8; ++t) {
      bool valid = (bv[t] >= 0.0f);
      unsigned long long key =
          ((unsigned long long)__float_as_uint(bv[t]) << 32) |
          (unsigned long long)(0xFFFFFFFFu - bj[t]);
      if (valid && key > best) best = key;
    }
#pragma unroll
    for (int d = 32; d >= 1; d >>= 1) {
      unsigned long long o = __shfl_xor(best, d);
      if (o > best) best = o;
    }
    unsigned wj = 0xFFFFFFFFu - (unsigned)(best & 0xFFFFFFFFull);
    if (lane == 0) t8i[row * 8 + pick] = wj;
#pragma unroll
    for (int t = 0; t < 8; ++t) if (bj[t] == wj) bv[t] = -1.0f;
  }
}

// ------- fp64-exact rerank -> exact top-4 — verbatim -------
__global__ __launch_bounds__(256) void rerank_k(const float* __restrict__ L,
                                                const float* __restrict__ U,
                                                const double* __restrict__ sqd,
                                                const unsigned* __restrict__ t8i,
                                                unsigned* __restrict__ t4i) {
  const int wave = threadIdx.x >> 6, lane = threadIdx.x & 63;
  const int row = blockIdx.x * 4 + wave;
  const float* xi = xrow(L, U, row);
  float xr[16];
#pragma unroll
  for (int t = 0; t < 16; ++t) xr[t] = xi[t * 64 + lane];
  unsigned cj[8];
  double cw[8];
#pragma unroll
  for (int c = 0; c < 8; ++c) cj[c] = t8i[row * 8 + c];
  for (int c = 0; c < 8; ++c) {
    const float* xj = xrow(L, U, (int)cj[c]);
    double s = 0.0;
#pragma unroll
    for (int t = 0; t < 16; ++t) s += (double)xr[t] * xj[t * 64 + lane];
#pragma unroll
    for (int d = 32; d >= 1; d >>= 1) s += __shfl_xor(s, d);
    double dist = (sqd[row] + sqd[cj[c]] - 2.0 * s) * (1.0 / 1024.0);
    cw[c] = exp(-0.5 * dist);
  }
  if (lane == 0) {
#pragma unroll
    for (int pick = 0; pick < 4; ++pick) {
      int ms = -1;
      double mv = -1.0;
      unsigned mj = 0xFFFFFFFFu;
#pragma unroll
      for (int c = 0; c < 8; ++c) {
        bool better = (cw[c] > mv) || (cw[c] == mv && cj[c] < mj);
        if (cw[c] >= 0.0 && better) { mv = cw[c]; mj = cj[c]; ms = c; }
      }
      t4i[row * 4 + pick] = mj;
      cw[ms] = -2.0;
    }
  }
}

// ------- count kept edges per row — verbatim -------
__global__ __launch_bounds__(256) void cnt4_k(const unsigned* __restrict__ t4i,
                                              unsigned* __restrict__ nn) {
  const int wave = threadIdx.x >> 6, lane = threadIdx.x & 63;
  const int i = blockIdx.x * 4 + wave;
  const uint4 mine = ((const uint4*)t4i)[i];
  unsigned base = 0;
  for (int j0 = 0; j0 < N_ALL; j0 += 64) {
    int j = j0 + lane;
    uint4 tj = ((const uint4*)t4i)[j];
    bool keep = (mine.x == (unsigned)j) | (mine.y == (unsigned)j) |
                (mine.z == (unsigned)j) | (mine.w == (unsigned)j) |
                (tj.x == (unsigned)i) | (tj.y == (unsigned)i) |
                (tj.z == (unsigned)i) | (tj.w == (unsigned)i);
    keep = keep && (j != i);
    base += (unsigned)__popcll(__ballot(keep));
  }
  if (lane == 0) nn[i] = base;
}

// ------- scan: rowPtr + groupBase (ELL-4) + label-layout probe -------
__global__ __launch_bounds__(64) void scanP_k(const unsigned* __restrict__ nn,
                                              unsigned* __restrict__ rowPtr,
                                              unsigned* __restrict__ gBase,
                                              const int* __restrict__ lab,
                                              int* __restrict__ labflag) {
  const int lane = threadIdx.x;
  const long long* l64 = (const long long*)lab;
  int bad = 0;
#pragma unroll
  for (int k = 0; k < 8; ++k) {
    long long v = l64[k * 64 + lane];
    if (v != 0 && v != 1) bad = 1;
  }
  unsigned long long bm = __ballot(bad);
  if (lane == 0) labflag[0] = (bm != 0ull) ? 0 : 1;
  unsigned running = 0, grun = 0;
  for (int j0 = 0; j0 < N_ALL; j0 += 64) {
    int v = (int)nn[j0 + lane];
    int gv = (v + 3) >> 2;
    int incl = v, gincl = gv;
#pragma unroll
    for (int d = 1; d < 64; d <<= 1) {
      int tA = __shfl_up(incl, d);
      int tB = __shfl_up(gincl, d);
      if (lane >= d) { incl += tA; gincl += tB; }
    }
    rowPtr[j0 + lane] = running + (unsigned)(incl - v);
    gBase[j0 + lane] = grun + (unsigned)(gincl - gv);
    running += (unsigned)__shfl(incl, 63);
    grun += (unsigned)__shfl(gincl, 63);
  }
  if (lane == 0) { rowPtr[N_ALL] = running; gBase[N_ALL] = grun; }
}

// ------- CSR index fill — verbatim -------
__global__ __launch_bounds__(256) void csrfill_k(const unsigned* __restrict__ t4i,
                                                 const unsigned* __restrict__ rowPtr,
                                                 Edge* __restrict__ edges,
                                                 unsigned* __restrict__ eRow) {
  const int wave = threadIdx.x >> 6, lane = threadIdx.x & 63;
  const int i = blockIdx.x * 4 + wave;
  const uint4 mine = ((const uint4*)t4i)[i];
  unsigned base = rowPtr[i];
  for (int j0 = 0; j0 < N_ALL; j0 += 64) {
    int j = j0 + lane;
    uint4 tj = ((const uint4*)t4i)[j];
    bool keep = (mine.x == (unsigned)j) | (mine.y == (unsigned)j) |
                (mine.z == (unsigned)j) | (mine.w == (unsigned)j) |
                (tj.x == (unsigned)i) | (tj.y == (unsigned)i) |
                (tj.z == (unsigned)i) | (tj.w == (unsigned)i);
    keep = keep && (j != i);
    unsigned long long m = __ballot(keep);
    if (keep) {
      unsigned pos = base + (unsigned)__popcll(m & ((1ull << lane) - 1ull));
      edges[pos].j = (unsigned)j;
      edges[pos].w = 0.0f;
      eRow[pos] = (unsigned)i;
    }
    base += (unsigned)__popcll(m);
  }
}

// ------- exact edge values — verbatim -------
__global__ __launch_bounds__(256) void edgeval_k(const float* __restrict__ L,
                                                 const float* __restrict__ U,
                                                 const double* __restrict__ sqd,
                                                 const unsigned* __restrict__ rowPtr,
                                                 const unsigned* __restrict__ eRow,
                                                 Edge* __restrict__ edges) {
  const int wave = threadIdx.x >> 6, lane = threadIdx.x & 63;
  const unsigned e = blockIdx.x * 4 + wave;
  if (e >= rowPtr[N_ALL]) return;
  const unsigned i = eRow[e];
  const unsigned j = edges[e].j;
  const float* xi = xrow(L, U, (int)i);
  const float* xj = xrow(L, U, (int)j);
  double s = 0.0;
#pragma unroll
  for (int t = 0; t < 16; ++t)
    s += (double)xi[t * 64 + lane] * xj[t * 64 + lane];
#pragma unroll
  for (int d = 32; d >= 1; d >>= 1) s += __shfl_xor(s, d);
  if (lane == 0) {
    double dist = (sqd[i] + sqd[j] - 2.0 * s) * (1.0 / 1024.0);
    edges[e].w = (float)exp(-0.5 * dist);
  }
}

// ------- degrees + ELL default-slot init -------
// Grid is 1024x256 = 262144 threads; first GCAP*4 = 49152 init one ELL slot
// each to {row=(g&0xFFF)<<16, w=0}: pad slots contribute 0*dsh[0]; fully-pad
// groups atomically add 0.0 to scattered rows (no same-address contention).
__global__ __launch_bounds__(256) void degE_k(const unsigned* __restrict__ rowPtr,
                                              const Edge* __restrict__ edges,
                                              float* __restrict__ Dis,
                                              uint2* __restrict__ ell) {
  const unsigned tid = blockIdx.x * 256 + threadIdx.x;
  if (tid < GCAP * 4) ell[tid] = make_uint2(((tid >> 2) & 0xFFFu) << 16, 0u);
  const int wave = threadIdx.x >> 6, lane = threadIdx.x & 63;
  const int i = blockIdx.x * 4 + wave;
  const unsigned b0 = rowPtr[i], b1 = rowPtr[i + 1];
  double ds = 0.0;
  for (unsigned e = b0 + lane; e < b1; e += 64) ds += (double)edges[e].w;
#pragma unroll
  for (int d = 32; d >= 1; d >>= 1) ds += __shfl_xor(ds, d);
  if (lane == 0) Dis[i] = (float)sqrt(1.0 / (ds + EPS_D));
}

// ------- scale + pack edges into ELL-4 groups -------
// Row i's edges occupy groups [gBase[i], gBase[i+1]); edge #pos of row i
// lands at slot (gBase[i]+pos/4)*4 + pos%4 as {(i<<16)|j, w_scaled}.
// Sum(ceil(deg/4)) <= E/4 + 3N/4 = 11264 < GCAP, so slots always fit.
__global__ __launch_bounds__(256) void pack_k(const unsigned* __restrict__ rowPtr,
                                              const unsigned* __restrict__ gBase,
                                              const unsigned* __restrict__ eRow,
                                              const float* __restrict__ Dis,
                                              const Edge* __restrict__ edges,
                                              uint2* __restrict__ ell) {
  const unsigned e = blockIdx.x * 256 + threadIdx.x;
  if (e >= rowPtr[N_ALL]) return;
  Edge ed = edges[e];
  const unsigned i = eRow[e];
  const float w = ed.w * Dis[i] * Dis[ed.j];
  const unsigned pos = e - rowPtr[i];
  const unsigned slot = (gBase[i] + (pos >> 2)) * 4 + (pos & 3u);
  if (slot < GCAP * 4) ell[slot] = make_uint2((i << 16) | ed.j, __float_as_uint(w));
}

// one ELL-4 group from two uint4 regs: A={m0,w0,m1,w1}, B={m2,w2,m3,w3}.
// Branch-free: 4 gathers, 8 FMAs, 2 unconditional LDS atomic adds. Slot 0
// is always a real edge (groups fill from slot 0), so row comes from A.x.
#define GRP(A, B)                                                         \
  do {                                                                    \
    const float2 d0_ = dsh[(A).x & 0xFFFu];                               \
    const float2 d1_ = dsh[(A).z & 0xFFFu];                               \
    const float2 d2_ = dsh[(B).x & 0xFFFu];                               \
    const float2 d3_ = dsh[(B).z & 0xFFFu];                               \
    const float w0_ = __uint_as_float((A).y);                             \
    const float w1_ = __uint_as_float((A).w);                             \
    const float w2_ = __uint_as_float((B).y);                             \
    const float w3_ = __uint_as_float((B).w);                             \
    const float sx_ = w0_ * d0_.x + w1_ * d1_.x + w2_ * d2_.x + w3_ * d3_.x; \
    const float sy_ = w0_ * d0_.y + w1_ * d1_.y + w2_ * d2_.y + w3_ * d3_.y; \
    const unsigned row_ = (A).x >> 16;                                    \
    atomicAdd(&acc[row_].x, sx_);                                         \
    atomicAdd(&acc[row_].y, sy_);                                         \
  } while (0)

// ------- persistent single-workgroup Chebyshev solver, v5 -------
// v4 post-mortem: 24K cy/iter, VALUBusy ~12% of the CU, bank conflicts only
// ~2.5K cy/iter -> the stall is the 32 divergent flush branches/thread that
// fragment scheduling regions and serialize (extract -> ds_read -> wait ->
// FMA -> exec-mask branch) per edge. v5: ELL-4 repack makes phase A fully
// straight-line: 12 groups/thread, each {4 gathers, 8 FMAs, 2 unconditional
// LDS atomicAdds}; zero branches, all groups independent -> compiler can
// batch the 24 uint4 L2 loads and pipeline 48 gathers. dreg dropped (phase
// B re-reads dsh[row]) to stay inside the 64-VGPR allocation.
__global__ __launch_bounds__(1024, 4) void chebsolve_k(
    const uint4* __restrict__ ell4,
    const int* __restrict__ lab,
    const int* __restrict__ labflag,
    float2* __restrict__ out) {
  __shared__ float2 dsh[N_ALL];   // 32 KB: d vector
  __shared__ float2 acc[N_ALL];   // 32 KB: per-row gather results
  const int t = threadIdx.x;

  float2 xv[4], rv[4];
  const int isI64 = labflag[0];

#pragma unroll
  for (int q = 0; q < 4; ++q) {
    const int row = t + q * 1024;
    float2 b = make_float2(0.0f, 0.0f);
    if (q == 0) {  // rows < N_LAB are exactly q==0
      int c = isI64 ? lab[2 * row] : lab[row];
      b.x = (c == 0) ? 1.0f : 0.0f;
      b.y = (c == 1) ? 1.0f : 0.0f;
    }
    xv[q] = make_float2(0.0f, 0.0f);
    rv[q] = b;
    dsh[row] = b;
    acc[row] = make_float2(0.0f, 0.0f);
  }
  __syncthreads();

  const double theta = 1.0, delta = 0.992;
  const double sigma1 = theta / delta;
  double rho = delta / theta;
  const uint4* ep = ell4 + (size_t)t * 24;  // 12 groups = 24 uint4 = 384 B

  for (int it = 0; it < NIT_CH; ++it) {
    const double rho_new = 1.0 / (2.0 * sigma1 - rho);
    const float c1 = (float)(rho_new * rho);
    const float c2 = (float)(2.0 * rho_new / delta);
    rho = rho_new;
    const bool last = (it == NIT_CH - 1);

    // ---- phase A: branch-free ELL-4 gather, ping-pong streamed ----
    uint4 a0 = ep[0], a1 = ep[1], a2 = ep[2], a3 = ep[3];
    uint4 b0 = ep[4], b1 = ep[5], b2 = ep[6], b3 = ep[7];
    GRP(a0, a1); GRP(a2, a3);
    a0 = ep[8]; a1 = ep[9]; a2 = ep[10]; a3 = ep[11];
    GRP(b0, b1); GRP(b2, b3);
    b0 = ep[12]; b1 = ep[13]; b2 = ep[14]; b3 = ep[15];
    GRP(a0, a1); GRP(a2, a3);
    a0 = ep[16]; a1 = ep[17]; a2 = ep[18]; a3 = ep[19];
    GRP(b0, b1); GRP(b2, b3);
    b0 = ep[20]; b1 = ep[21]; b2 = ep[22]; b3 = ep[23];
    GRP(a0, a1); GRP(a2, a3);
    GRP(b0, b1); GRP(b2, b3);
    __syncthreads();  // all atomics visible before row-owned update

    // ---- phase B: row-owned update; re-zero acc for next iteration ----
#pragma unroll
    for (int q = 0; q < 4; ++q) {
      const int row = t + q * 1024;
      const float2 a = acc[row];
      acc[row] = make_float2(0.0f, 0.0f);
      const float2 di = dsh[row];
      xv[q].x += di.x;
      xv[q].y += di.y;
      rv[q].x += ALPHA_ * a.x - di.x;
      rv[q].y += ALPHA_ * a.y - di.y;
      if (!last) {
        float2 dn;
        dn.x = c1 * di.x + c2 * rv[q].x;
        dn.y = c1 * di.y + c2 * rv[q].y;
        dsh[row] = dn;
      }
    }
    __syncthreads();  // d + zeroed acc visible before next gather
  }

#pragma unroll
  for (int q = 1; q < 4; ++q) {
    const int row = t + q * 1024;
    out[row - N_LAB] = xv[q];
  }
}

// ---------------- launch ----------------
extern "C" void kernel_launch(void* const* d_in, const int* in_sizes, int n_in,
                              void* d_out, int out_size, void* d_ws, size_t ws_size,
                              hipStream_t stream) {
  int iL = 0, iT = 1, iU = 2;
  for (int i = 0; i < n_in; ++i) {
    if (in_sizes[i] == N_LAB * DIMF) iL = i;
    else if (in_sizes[i] == (N_ALL - N_LAB) * DIMF) iU = i;
    else iT = i;
  }
  const float* L = (const float*)d_in[iL];
  const int* lab = (const int*)d_in[iT];
  const float* U = (const float*)d_in[iU];
  float2* out = (float2*)d_out;

  char* w = (char*)d_ws;
  size_t off = 0;
  auto alloc = [&](size_t bytes) {
    void* p = (void*)(w + off);
    off += (bytes + 255) & ~(size_t)255;
    return p;
  };
  _Float16* Wh = (_Float16*)alloc((size_t)N_ALL * N_ALL * 2);     // 32 MB proxy
  unsigned short* Xbf = (unsigned short*)alloc((size_t)N_ALL * DIMF * 2);  // 8 MB
  float* sq = (float*)alloc(N_ALL * 4);
  double* sqd = (double*)alloc(N_ALL * 8);
  unsigned* t8i = (unsigned*)alloc(N_ALL * 8 * 4);
  unsigned* t4i = (unsigned*)alloc(N_ALL * 4 * 4);
  float* Dis = (float*)alloc(N_ALL * 4);
  unsigned* nn = (unsigned*)alloc(N_ALL * 4);
  unsigned* rowPtr = (unsigned*)alloc((N_ALL + 1) * 4);
  unsigned* gBase = (unsigned*)alloc((N_ALL + 1) * 4);
  int* labflag = (int*)alloc(256);
  Edge* edges = (Edge*)alloc((size_t)EDGECAP * sizeof(Edge));     // 256 KB
  unsigned* eRow = (unsigned*)alloc((size_t)EDGECAP * 4);         // 128 KB
  uint2* ell = (uint2*)alloc((size_t)GCAP * 4 * 8);               // 384 KB ELL-4
  if (off > ws_size) return;

  prep_k<<<N_ALL, 256, 0, stream>>>(L, U, Xbf, sq, sqd);
  gemm_w<<<dim3(32, 32), 256, 0, stream>>>(Xbf, sq, Wh);
  top8_k<<<N_ALL / 4, 256, 0, stream>>>(Wh, t8i);
  rerank_k<<<N_ALL / 4, 256, 0, stream>>>(L, U, sqd, t8i, t4i);
  cnt4_k<<<N_ALL / 4, 256, 0, stream>>>(t4i, nn);
  scanP_k<<<1, 64, 0, stream>>>(nn, rowPtr, gBase, lab, labflag);
  csrfill_k<<<N_ALL / 4, 256, 0, stream>>>(t4i, rowPtr, edges, eRow);
  edgeval_k<<<EDGECAP / 4, 256, 0, stream>>>(L, U, sqd, rowPtr, eRow, edges);
  degE_k<<<N_ALL / 4, 256, 0, stream>>>(rowPtr, edges, Dis, ell);
  pack_k<<<EDGECAP / 256, 256, 0, stream>>>(rowPtr, gBase, eRow, Dis, edges, ell);
  chebsolve_k<<<1, 1024, 0, stream>>>((const uint4*)ell, lab, labflag, out);
}

// Round 6
// 1120.303 us; speedup vs baseline: 2.6536x; 2.6536x over previous
//
#include <hip/hip_runtime.h>

#define N_ALL 4096
#define N_LAB 1024
#define DIMF 1024
#define EDGECAP 32768
#define GCAP 11264   // = E/4 + 3N/4 worst case = 11 groups x 1024 threads
#define ALPHA_ 0.99f
#define NIT_CH 80
#define EPS_D 2.220446049250313e-16

typedef short bf16x8 __attribute__((ext_vector_type(8)));
typedef float f32x4 __attribute__((ext_vector_type(4)));

struct __align__(8) Edge { unsigned j; float w; };

__device__ inline const float* xrow(const float* L, const float* U, int r) {
  return (r < N_LAB) ? (L + (size_t)r * DIMF) : (U + (size_t)(r - N_LAB) * DIMF);
}

__device__ inline void load_lds16(const void* g, void* l) {
  __builtin_amdgcn_global_load_lds(
      (const __attribute__((address_space(1))) unsigned int*)g,
      (__attribute__((address_space(3))) unsigned int*)l, 16, 0, 0);
}

__device__ inline unsigned short bf16rne(float f) {
  unsigned u = __float_as_uint(f);
  unsigned r = (u + 0x7fffu + ((u >> 16) & 1u)) >> 16;
  return (unsigned short)r;
}

// ------- prep: fp32 -> bf16 copy + fp32 & fp64 row norms — verbatim -------
__global__ __launch_bounds__(256) void prep_k(const float* __restrict__ L,
                                              const float* __restrict__ U,
                                              unsigned short* __restrict__ Xbf,
                                              float* __restrict__ sq,
                                              double* __restrict__ sqd) {
  const int row = blockIdx.x;
  const int tid = threadIdx.x;
  const float* src = xrow(L, U, row);
  float4 v = ((const float4*)src)[tid];
  ushort4 h;
  h.x = bf16rne(v.x); h.y = bf16rne(v.y); h.z = bf16rne(v.z); h.w = bf16rne(v.w);
  ((ushort4*)(Xbf + (size_t)row * DIMF))[tid] = h;
  float s = v.x * v.x + v.y * v.y + v.z * v.z + v.w * v.w;
  double sd = (double)v.x * v.x + (double)v.y * v.y +
              (double)v.z * v.z + (double)v.w * v.w;
#pragma unroll
  for (int d = 32; d >= 1; d >>= 1) {
    s += __shfl_xor(s, d);
    sd += __shfl_xor(sd, d);
  }
  __shared__ float wsum[4];
  __shared__ double wsumd[4];
  if ((tid & 63) == 0) { wsum[tid >> 6] = s; wsumd[tid >> 6] = sd; }
  __syncthreads();
  if (tid == 0) {
    sq[row] = wsum[0] + wsum[1] + wsum[2] + wsum[3];
    sqd[row] = wsumd[0] + wsumd[1] + wsumd[2] + wsumd[3];
  }
}

// ------- MFMA bf16 gram -> fp16 RANKING PROXY — verbatim -------
__global__ __launch_bounds__(256) void gemm_w(const unsigned short* __restrict__ Xbf,
                                              const float* __restrict__ sq,
                                              _Float16* __restrict__ Wh) {
  __shared__ unsigned short At[128 * 32];
  __shared__ unsigned short Bt[128 * 32];
  const int tid = threadIdx.x;
  const int wave = tid >> 6, lane = tid & 63;
  const int brow = blockIdx.y * 128, bcol = blockIdx.x * 128;
  const int q = lane >> 4, rl = lane & 15;
  const int wr = (wave >> 1) * 64, wc = (wave & 1) * 64;

  f32x4 acc[4][4] = {};

  const int srow = tid >> 2;
  const int soff = (tid & 3) * 8;

  for (int k0 = 0; k0 < DIMF; k0 += 32) {
#pragma unroll
    for (int half = 0; half < 2; ++half) {
      const unsigned short* ga =
          Xbf + (size_t)(brow + half * 64 + srow) * DIMF + k0 + soff;
      load_lds16(ga, &At[(half * 64 + wave * 16) * 32]);
      const unsigned short* gb =
          Xbf + (size_t)(bcol + half * 64 + srow) * DIMF + k0 + soff;
      load_lds16(gb, &Bt[(half * 64 + wave * 16) * 32]);
    }
    __syncthreads();
    bf16x8 af[4], bf_[4];
#pragma unroll
    for (int t = 0; t < 4; ++t) {
      af[t] = *(const bf16x8*)&At[(wr + t * 16 + rl) * 32 + q * 8];
      bf_[t] = *(const bf16x8*)&Bt[(wc + t * 16 + rl) * 32 + q * 8];
    }
#pragma unroll
    for (int i = 0; i < 4; ++i)
#pragma unroll
      for (int j = 0; j < 4; ++j)
        acc[i][j] = __builtin_amdgcn_mfma_f32_16x16x32_bf16(af[i], bf_[j], acc[i][j], 0, 0, 0);
    __syncthreads();
  }

#pragma unroll
  for (int i = 0; i < 4; ++i) {
#pragma unroll
    for (int j = 0; j < 4; ++j) {
#pragma unroll
      for (int reg = 0; reg < 4; ++reg) {
        int gr = brow + wr + i * 16 + q * 4 + reg;
        int gc = bcol + wc + j * 16 + rl;
        float g = acc[i][j][reg];
        float dist = sq[gr] + sq[gc] - 2.0f * g;   // unnormalized
        float val = fmaxf(2600.0f - dist, 0.25f);
        if (gr == gc) val = 0.0f;
        Wh[(size_t)gr * N_ALL + gc] = (_Float16)val;
      }
    }
  }
}

// ------- top-8 candidates per row (fp16 proxy), single scan — verbatim -------
__global__ __launch_bounds__(256) void top8_k(const _Float16* __restrict__ Wh,
                                              unsigned* __restrict__ t8i) {
  const int wave = threadIdx.x >> 6, lane = threadIdx.x & 63;
  const int row = blockIdx.x * 4 + wave;
  const _Float16* Wr = Wh + (size_t)row * N_ALL;
  float bv[8]; unsigned bj[8];
#pragma unroll
  for (int t = 0; t < 8; ++t) { bv[t] = -1.0f; bj[t] = 0xFFFFFFFFu; }
  float minv = -1.0f; int mins = 0;
  for (int s = 0; s < 64; ++s) {
    int j = s * 64 + lane;
    float v = (float)Wr[j];
    if (v > minv) {
#pragma unroll
      for (int t = 0; t < 8; ++t) if (t == mins) { bv[t] = v; bj[t] = (unsigned)j; }
      minv = bv[0]; mins = 0;
#pragma unroll
      for (int t = 1; t < 8; ++t) if (bv[t] < minv) { minv = bv[t]; mins = t; }
    }
  }
  for (int pick = 0; pick < 8; ++pick) {
    unsigned long long best = 0;
#pragma unroll
    for (int t = 0; t < 8; ++t) {
      bool valid = (bv[t] >= 0.0f);
      unsigned long long key =
          ((unsigned long long)__float_as_uint(bv[t]) << 32) |
          (unsigned long long)(0xFFFFFFFFu - bj[t]);
      if (valid && key > best) best = key;
    }
#pragma unroll
    for (int d = 32; d >= 1; d >>= 1) {
      unsigned long long o = __shfl_xor(best, d);
      if (o > best) best = o;
    }
    unsigned wj = 0xFFFFFFFFu - (unsigned)(best & 0xFFFFFFFFull);
    if (lane == 0) t8i[row * 8 + pick] = wj;
#pragma unroll
    for (int t = 0; t < 8; ++t) if (bj[t] == wj) bv[t] = -1.0f;
  }
}

// ------- fp64-exact rerank -> exact top-4 — verbatim -------
__global__ __launch_bounds__(256) void rerank_k(const float* __restrict__ L,
                                                const float* __restrict__ U,
                                                const double* __restrict__ sqd,
                                                const unsigned* __restrict__ t8i,
                                                unsigned* __restrict__ t4i) {
  const int wave = threadIdx.x >> 6, lane = threadIdx.x & 63;
  const int row = blockIdx.x * 4 + wave;
  const float* xi = xrow(L, U, row);
  float xr[16];
#pragma unroll
  for (int t = 0; t < 16; ++t) xr[t] = xi[t * 64 + lane];
  unsigned cj[8];
  double cw[8];
#pragma unroll
  for (int c = 0; c < 8; ++c) cj[c] = t8i[row * 8 + c];
  for (int c = 0; c < 8; ++c) {
    const float* xj = xrow(L, U, (int)cj[c]);
    double s = 0.0;
#pragma unroll
    for (int t = 0; t < 16; ++t) s += (double)xr[t] * xj[t * 64 + lane];
#pragma unroll
    for (int d = 32; d >= 1; d >>= 1) s += __shfl_xor(s, d);
    double dist = (sqd[row] + sqd[cj[c]] - 2.0 * s) * (1.0 / 1024.0);
    cw[c] = exp(-0.5 * dist);
  }
  if (lane == 0) {
#pragma unroll
    for (int pick = 0; pick < 4; ++pick) {
      int ms = -1;
      double mv = -1.0;
      unsigned mj = 0xFFFFFFFFu;
#pragma unroll
      for (int c = 0; c < 8; ++c) {
        bool better = (cw[c] > mv) || (cw[c] == mv && cj[c] < mj);
        if (cw[c] >= 0.0 && better) { mv = cw[c]; mj = cj[c]; ms = c; }
      }
      t4i[row * 4 + pick] = mj;
      cw[ms] = -2.0;
    }
  }
}

// ------- count kept edges per row — verbatim -------
__global__ __launch_bounds__(256) void cnt4_k(const unsigned* __restrict__ t4i,
                                              unsigned* __restrict__ nn) {
  const int wave = threadIdx.x >> 6, lane = threadIdx.x & 63;
  const int i = blockIdx.x * 4 + wave;
  const uint4 mine = ((const uint4*)t4i)[i];
  unsigned base = 0;
  for (int j0 = 0; j0 < N_ALL; j0 += 64) {
    int j = j0 + lane;
    uint4 tj = ((const uint4*)t4i)[j];
    bool keep = (mine.x == (unsigned)j) | (mine.y == (unsigned)j) |
                (mine.z == (unsigned)j) | (mine.w == (unsigned)j) |
                (tj.x == (unsigned)i) | (tj.y == (unsigned)i) |
                (tj.z == (unsigned)i) | (tj.w == (unsigned)i);
    keep = keep && (j != i);
    base += (unsigned)__popcll(__ballot(keep));
  }
  if (lane == 0) nn[i] = base;
}

// ------- scan: rowPtr + groupBase (ELL-4) + label-layout probe -------
__global__ __launch_bounds__(64) void scanP_k(const unsigned* __restrict__ nn,
                                              unsigned* __restrict__ rowPtr,
                                              unsigned* __restrict__ gBase,
                                              const int* __restrict__ lab,
                                              int* __restrict__ labflag) {
  const int lane = threadIdx.x;
  const long long* l64 = (const long long*)lab;
  int bad = 0;
#pragma unroll
  for (int k = 0; k < 8; ++k) {
    long long v = l64[k * 64 + lane];
    if (v != 0 && v != 1) bad = 1;
  }
  unsigned long long bm = __ballot(bad);
  if (lane == 0) labflag[0] = (bm != 0ull) ? 0 : 1;
  unsigned running = 0, grun = 0;
  for (int j0 = 0; j0 < N_ALL; j0 += 64) {
    int v = (int)nn[j0 + lane];
    int gv = (v + 3) >> 2;
    int incl = v, gincl = gv;
#pragma unroll
    for (int d = 1; d < 64; d <<= 1) {
      int tA = __shfl_up(incl, d);
      int tB = __shfl_up(gincl, d);
      if (lane >= d) { incl += tA; gincl += tB; }
    }
    rowPtr[j0 + lane] = running + (unsigned)(incl - v);
    gBase[j0 + lane] = grun + (unsigned)(gincl - gv);
    running += (unsigned)__shfl(incl, 63);
    grun += (unsigned)__shfl(gincl, 63);
  }
  if (lane == 0) { rowPtr[N_ALL] = running; gBase[N_ALL] = grun; }
}

// ------- CSR index fill — verbatim -------
__global__ __launch_bounds__(256) void csrfill_k(const unsigned* __restrict__ t4i,
                                                 const unsigned* __restrict__ rowPtr,
                                                 Edge* __restrict__ edges,
                                                 unsigned* __restrict__ eRow) {
  const int wave = threadIdx.x >> 6, lane = threadIdx.x & 63;
  const int i = blockIdx.x * 4 + wave;
  const uint4 mine = ((const uint4*)t4i)[i];
  unsigned base = rowPtr[i];
  for (int j0 = 0; j0 < N_ALL; j0 += 64) {
    int j = j0 + lane;
    uint4 tj = ((const uint4*)t4i)[j];
    bool keep = (mine.x == (unsigned)j) | (mine.y == (unsigned)j) |
                (mine.z == (unsigned)j) | (mine.w == (unsigned)j) |
                (tj.x == (unsigned)i) | (tj.y == (unsigned)i) |
                (tj.z == (unsigned)i) | (tj.w == (unsigned)i);
    keep = keep && (j != i);
    unsigned long long m = __ballot(keep);
    if (keep) {
      unsigned pos = base + (unsigned)__popcll(m & ((1ull << lane) - 1ull));
      edges[pos].j = (unsigned)j;
      edges[pos].w = 0.0f;
      eRow[pos] = (unsigned)i;
    }
    base += (unsigned)__popcll(m);
  }
}

// ------- exact edge values — verbatim -------
__global__ __launch_bounds__(256) void edgeval_k(const float* __restrict__ L,
                                                 const float* __restrict__ U,
                                                 const double* __restrict__ sqd,
                                                 const unsigned* __restrict__ rowPtr,
                                                 const unsigned* __restrict__ eRow,
                                                 Edge* __restrict__ edges) {
  const int wave = threadIdx.x >> 6, lane = threadIdx.x & 63;
  const unsigned e = blockIdx.x * 4 + wave;
  if (e >= rowPtr[N_ALL]) return;
  const unsigned i = eRow[e];
  const unsigned j = edges[e].j;
  const float* xi = xrow(L, U, (int)i);
  const float* xj = xrow(L, U, (int)j);
  double s = 0.0;
#pragma unroll
  for (int t = 0; t < 16; ++t)
    s += (double)xi[t * 64 + lane] * xj[t * 64 + lane];
#pragma unroll
  for (int d = 32; d >= 1; d >>= 1) s += __shfl_xor(s, d);
  if (lane == 0) {
    double dist = (sqd[i] + sqd[j] - 2.0 * s) * (1.0 / 1024.0);
    edges[e].w = (float)exp(-0.5 * dist);
  }
}

// ------- degrees + ELL slot default init ({j=0, w=0}) -------
// Pad slots inside real groups contribute w*dsh[0] = 0 to their group sum;
// pad groups produce gsum entries no row ever reads (gBase ranges cover
// only real groups). First GCAP*4 threads of this 262144-thread grid init.
__global__ __launch_bounds__(256) void degE_k(const unsigned* __restrict__ rowPtr,
                                              const Edge* __restrict__ edges,
                                              float* __restrict__ Dis,
                                              uint2* __restrict__ ell) {
  const unsigned tid = blockIdx.x * 256 + threadIdx.x;
  if (tid < GCAP * 4) ell[tid] = make_uint2(0u, 0u);
  const int wave = threadIdx.x >> 6, lane = threadIdx.x & 63;
  const int i = blockIdx.x * 4 + wave;
  const unsigned b0 = rowPtr[i], b1 = rowPtr[i + 1];
  double ds = 0.0;
  for (unsigned e = b0 + lane; e < b1; e += 64) ds += (double)edges[e].w;
#pragma unroll
  for (int d = 32; d >= 1; d >>= 1) ds += __shfl_xor(ds, d);
  if (lane == 0) Dis[i] = (float)sqrt(1.0 / (ds + EPS_D));
}

// ------- scale + pack edges into ELL-4 groups ({j, w}) -------
// Row i's edges occupy groups [gBase[i], gBase[i+1]); edge #pos of row i
// lands at slot (gBase[i]+pos/4)*4 + pos%4. Sum(ceil(deg/4)) <= E/4+3N/4
// = 11264 = GCAP, so slots always fit.
__global__ __launch_bounds__(256) void pack_k(const unsigned* __restrict__ rowPtr,
                                              const unsigned* __restrict__ gBase,
                                              const unsigned* __restrict__ eRow,
                                              const float* __restrict__ Dis,
                                              const Edge* __restrict__ edges,
                                              uint2* __restrict__ ell) {
  const unsigned e = blockIdx.x * 256 + threadIdx.x;
  if (e >= rowPtr[N_ALL]) return;
  Edge ed = edges[e];
  const unsigned i = eRow[e];
  const float w = ed.w * Dis[i] * Dis[ed.j];
  const unsigned pos = e - rowPtr[i];
  const unsigned slot = (gBase[i] + (pos >> 2)) * 4 + (pos & 3u);
  if (slot < GCAP * 4) ell[slot] = make_uint2(ed.j, __float_as_uint(w));
}

// ------- persistent single-workgroup Chebyshev solver, v6 -------
// v5 post-mortem: unconditional LDS float atomicAdd (24.6K/iter) cost ~160
// cy per wave-level atomic (CAS-loop + same-address storms on hub rows'
// consecutive groups) -> 3.4x regression. v6 keeps the branch-free ELL-4
// gather but writes each group's sum to its OWN LDS slot gsum[g] (plain
// ds_write_b64, owner-unique: zero atomics, zero contention, zero
// divergence). Group ownership interleaved (g = t + 1024k) so gsum writes
// are lane-consecutive (conflict-free) and ell loads coalesce. The per-row
// reduction moves to phase B: row owner sums gsum[gBase[i]..gBase[i+1]),
// 8-wide unrolled predicated INDEPENDENT reads (hub ~75 groups -> ~10
// pipelined rounds; median 1). gsum is fully overwritten each iteration,
// so no re-zero pass. LDS: 32KB dsh + 88KB gsum = 120KB.
__global__ __launch_bounds__(1024, 4) void chebsolve_k(
    const uint4* __restrict__ ell4,
    const int* __restrict__ lab,
    const int* __restrict__ labflag,
    const unsigned* __restrict__ gBase,
    float2* __restrict__ out) {
  __shared__ float2 dsh[N_ALL];        // 32 KB: d vector
  __shared__ float2 gsum[GCAP + 8];    // 88 KB: per-group partial sums
  const int t = threadIdx.x;

  float2 xv[4], rv[4];
  unsigned g0q[4], g1q[4];
  const int isI64 = labflag[0];

#pragma unroll
  for (int q = 0; q < 4; ++q) {
    const int row = t + q * 1024;
    float2 b = make_float2(0.0f, 0.0f);
    if (q == 0) {  // rows < N_LAB are exactly q==0
      int c = isI64 ? lab[2 * row] : lab[row];
      b.x = (c == 0) ? 1.0f : 0.0f;
      b.y = (c == 1) ? 1.0f : 0.0f;
    }
    xv[q] = make_float2(0.0f, 0.0f);
    rv[q] = b;
    dsh[row] = b;
    g0q[q] = gBase[row];
    g1q[q] = gBase[row + 1];
  }
  __syncthreads();

  const double theta = 1.0, delta = 0.992;
  const double sigma1 = theta / delta;
  double rho = delta / theta;
  const uint4* ep = ell4 + (size_t)t * 2;  // group g slots at ell4[2g], ell4[2g+1]

  for (int it = 0; it < NIT_CH; ++it) {
    const double rho_new = 1.0 / (2.0 * sigma1 - rho);
    const float c1 = (float)(rho_new * rho);
    const float c2 = (float)(2.0 * rho_new / delta);
    rho = rho_new;
    const bool last = (it == NIT_CH - 1);

    // ---- phase A: branch-free gather; each group -> private gsum slot ----
#pragma unroll
    for (int k = 0; k < GCAP / 1024; ++k) {
      const uint4 A = ep[(size_t)k * 2048];
      const uint4 B = ep[(size_t)k * 2048 + 1];
      const float2 d0 = dsh[A.x & 0xFFFu];
      const float2 d1 = dsh[A.z & 0xFFFu];
      const float2 d2 = dsh[B.x & 0xFFFu];
      const float2 d3 = dsh[B.z & 0xFFFu];
      const float w0 = __uint_as_float(A.y);
      const float w1 = __uint_as_float(A.w);
      const float w2 = __uint_as_float(B.y);
      const float w3 = __uint_as_float(B.w);
      const float sx = w0 * d0.x + w1 * d1.x + w2 * d2.x + w3 * d3.x;
      const float sy = w0 * d0.y + w1 * d1.y + w2 * d2.y + w3 * d3.y;
      gsum[t + k * 1024] = make_float2(sx, sy);
    }
    __syncthreads();  // all group sums visible

    // ---- phase B: row-owned reduction over gsum + x/r/d update ----
#pragma unroll
    for (int q = 0; q < 4; ++q) {
      const int row = t + q * 1024;
      float ax = 0.0f, ay = 0.0f;
      const unsigned g1 = g1q[q];
      for (unsigned g = g0q[q]; g < g1; g += 8) {
        const float2 s0 = gsum[g];
        const float2 s1 = gsum[g + 1];
        const float2 s2 = gsum[g + 2];
        const float2 s3 = gsum[g + 3];
        const float2 s4 = gsum[g + 4];
        const float2 s5 = gsum[g + 5];
        const float2 s6 = gsum[g + 6];
        const float2 s7 = gsum[g + 7];
        ax += s0.x; ay += s0.y;
        if (g + 1 < g1) { ax += s1.x; ay += s1.y; }
        if (g + 2 < g1) { ax += s2.x; ay += s2.y; }
        if (g + 3 < g1) { ax += s3.x; ay += s3.y; }
        if (g + 4 < g1) { ax += s4.x; ay += s4.y; }
        if (g + 5 < g1) { ax += s5.x; ay += s5.y; }
        if (g + 6 < g1) { ax += s6.x; ay += s6.y; }
        if (g + 7 < g1) { ax += s7.x; ay += s7.y; }
      }
      const float2 di = dsh[row];
      xv[q].x += di.x;
      xv[q].y += di.y;
      rv[q].x += ALPHA_ * ax - di.x;
      rv[q].y += ALPHA_ * ay - di.y;
      if (!last) {
        float2 dn;
        dn.x = c1 * di.x + c2 * rv[q].x;
        dn.y = c1 * di.y + c2 * rv[q].y;
        dsh[row] = dn;
      }
    }
    __syncthreads();  // updated d visible before next gather
  }

#pragma unroll
  for (int q = 1; q < 4; ++q) {
    const int row = t + q * 1024;
    out[row - N_LAB] = xv[q];
  }
}

// ---------------- launch ----------------
extern "C" void kernel_launch(void* const* d_in, const int* in_sizes, int n_in,
                              void* d_out, int out_size, void* d_ws, size_t ws_size,
                              hipStream_t stream) {
  int iL = 0, iT = 1, iU = 2;
  for (int i = 0; i < n_in; ++i) {
    if (in_sizes[i] == N_LAB * DIMF) iL = i;
    else if (in_sizes[i] == (N_ALL - N_LAB) * DIMF) iU = i;
    else iT = i;
  }
  const float* L = (const float*)d_in[iL];
  const int* lab = (const int*)d_in[iT];
  const float* U = (const float*)d_in[iU];
  float2* out = (float2*)d_out;

  char* w = (char*)d_ws;
  size_t off = 0;
  auto alloc = [&](size_t bytes) {
    void* p = (void*)(w + off);
    off += (bytes + 255) & ~(size_t)255;
    return p;
  };
  _Float16* Wh = (_Float16*)alloc((size_t)N_ALL * N_ALL * 2);     // 32 MB proxy
  unsigned short* Xbf = (unsigned short*)alloc((size_t)N_ALL * DIMF * 2);  // 8 MB
  float* sq = (float*)alloc(N_ALL * 4);
  double* sqd = (double*)alloc(N_ALL * 8);
  unsigned* t8i = (unsigned*)alloc(N_ALL * 8 * 4);
  unsigned* t4i = (unsigned*)alloc(N_ALL * 4 * 4);
  float* Dis = (float*)alloc(N_ALL * 4);
  unsigned* nn = (unsigned*)alloc(N_ALL * 4);
  unsigned* rowPtr = (unsigned*)alloc((N_ALL + 1) * 4);
  unsigned* gBase = (unsigned*)alloc((N_ALL + 1) * 4);
  int* labflag = (int*)alloc(256);
  Edge* edges = (Edge*)alloc((size_t)EDGECAP * sizeof(Edge));     // 256 KB
  unsigned* eRow = (unsigned*)alloc((size_t)EDGECAP * 4);         // 128 KB
  uint2* ell = (uint2*)alloc((size_t)GCAP * 4 * 8);               // 352 KB ELL-4
  if (off > ws_size) return;

  prep_k<<<N_ALL, 256, 0, stream>>>(L, U, Xbf, sq, sqd);
  gemm_w<<<dim3(32, 32), 256, 0, stream>>>(Xbf, sq, Wh);
  top8_k<<<N_ALL / 4, 256, 0, stream>>>(Wh, t8i);
  rerank_k<<<N_ALL / 4, 256, 0, stream>>>(L, U, sqd, t8i, t4i);
  cnt4_k<<<N_ALL / 4, 256, 0, stream>>>(t4i, nn);
  scanP_k<<<1, 64, 0, stream>>>(nn, rowPtr, gBase, lab, labflag);
  csrfill_k<<<N_ALL / 4, 256, 0, stream>>>(t4i, rowPtr, edges, eRow);
  edgeval_k<<<EDGECAP / 4, 256, 0, stream>>>(L, U, sqd, rowPtr, eRow, edges);
  degE_k<<<N_ALL / 4, 256, 0, stream>>>(rowPtr, edges, Dis, ell);
  pack_k<<<EDGECAP / 256, 256, 0, stream>>>(rowPtr, gBase, eRow, Dis, edges, ell);
  chebsolve_k<<<1, 1024, 0, stream>>>((const uint4*)ell, lab, labflag, gBase, out);
}